// Round 7
// baseline (468.606 us; speedup 1.0000x reference)
//
#include <hip/hip_runtime.h>
#include <hip/hip_fp16.h>

#define HDIM 32
#define IN_DIM 128
#define NEG_SLOPE 0.2f
#define NPB 128            // nodes per coarse bucket (power of 2)
#define NPB_SHIFT 7
#define MAXB 1024          // max buckets (B = ceil(N/128) = 782)
#define CHUNK 8192         // edges per chunk block
#define CAP 4096           // max records per bucket for LDS sort fast path
#define TROWS 64           // GEMM tile rows

__device__ __forceinline__ float leaky(float e) {
    return (e >= 0.f) ? e : NEG_SLOPE * e;
}

__device__ __forceinline__ float2 h2f(unsigned int u) {
    __half2 h = *reinterpret_cast<__half2*>(&u);
    return __half22float2(h);
}

struct Acc8 {
    float a0, a1, a2, a3, a4, a5, a6, a7;
    __device__ __forceinline__ void init() { a0=a1=a2=a3=a4=a5=a6=a7=0.f; }
    __device__ __forceinline__ void fma(uint4 u, float wt) {
        float2 f0 = h2f(u.x), f1 = h2f(u.y), f2 = h2f(u.z), f3 = h2f(u.w);
        a0 += wt * f0.x; a1 += wt * f0.y; a2 += wt * f1.x; a3 += wt * f1.y;
        a4 += wt * f2.x; a5 += wt * f2.y; a6 += wt * f3.x; a7 += wt * f3.y;
    }
};

// ---------------- GEMM kernels: 64-row tile, 8 outputs/thread -------------

__global__ __launch_bounds__(256) void gemm128(
    const float* __restrict__ x, const float* __restrict__ W,
    const float* __restrict__ a_s, const float* __restrict__ a_d,
    __half* __restrict__ h, float* __restrict__ es, float* __restrict__ ed, int N)
{
    __shared__ float Ws[IN_DIM * HDIM];      // 16 KB, [k][col]
    __shared__ float xs[TROWS][IN_DIM];      // 32 KB
    const int tid = threadIdx.x;
    for (int i = tid; i < IN_DIM * HDIM; i += 256) Ws[i] = W[i];
    const int col = tid & 31;
    const int rg  = tid >> 5;                // 0..7 -> rows rg*8..rg*8+7
    const float as_c = a_s[col], ad_c = a_d[col];
    const int ntiles = (N + TROWS - 1) / TROWS;
    for (int tile = blockIdx.x; tile < ntiles; tile += gridDim.x) {
        const int row0 = tile * TROWS;
        __syncthreads();
        const float4* x4 = (const float4*)(x + (size_t)row0 * IN_DIM);
        const int nvec = TROWS * IN_DIM / 4;  // 2048
        if (row0 + TROWS <= N) {
            for (int i = tid; i < nvec; i += 256) ((float4*)xs)[i] = x4[i];
        } else {
            for (int i = tid; i < nvec; i += 256) {
                int r = i >> 5;               // i/(IN_DIM/4)
                ((float4*)xs)[i] = (row0 + r < N) ? x4[i] : make_float4(0,0,0,0);
            }
        }
        __syncthreads();
        float acc[8];
        #pragma unroll
        for (int r = 0; r < 8; r++) acc[r] = 0.f;
        const int rbase = rg * 8;
        for (int k = 0; k < IN_DIM; k += 4) {
            float w0 = Ws[(k+0)*HDIM + col];
            float w1 = Ws[(k+1)*HDIM + col];
            float w2 = Ws[(k+2)*HDIM + col];
            float w3 = Ws[(k+3)*HDIM + col];
            #pragma unroll
            for (int r = 0; r < 8; r++) {
                float4 xv = *(const float4*)&xs[rbase + r][k];
                acc[r] += xv.x*w0 + xv.y*w1 + xv.z*w2 + xv.w*w3;
            }
        }
        #pragma unroll
        for (int r = 0; r < 8; r++) {
            int row = row0 + rbase + r;
            float ps = acc[r] * as_c, pd = acc[r] * ad_c;
            #pragma unroll
            for (int m = 16; m >= 1; m >>= 1) { ps += __shfl_xor(ps, m); pd += __shfl_xor(pd, m); }
            if (row < N) {
                h[(size_t)row * HDIM + col] = __float2half(acc[r]);
                if (col == 0) { es[row] = ps; ed[row] = pd; }
            }
        }
    }
}

__global__ __launch_bounds__(256) void gemm32(
    const float* __restrict__ x, const float* __restrict__ W,
    const float* __restrict__ a_s, const float* __restrict__ a_d,
    __half* __restrict__ h, float* __restrict__ es, float* __restrict__ ed, int N)
{
    __shared__ float Ws[HDIM * HDIM];        // 4 KB
    __shared__ float xs[TROWS][HDIM];        // 8 KB
    const int tid = threadIdx.x;
    for (int i = tid; i < HDIM * HDIM; i += 256) Ws[i] = W[i];
    const int col = tid & 31;
    const int rg  = tid >> 5;
    const float as_c = a_s[col], ad_c = a_d[col];
    const int ntiles = (N + TROWS - 1) / TROWS;
    for (int tile = blockIdx.x; tile < ntiles; tile += gridDim.x) {
        const int row0 = tile * TROWS;
        __syncthreads();
        const float4* x4 = (const float4*)(x + (size_t)row0 * HDIM);
        const int nvec = TROWS * HDIM / 4;   // 512
        if (row0 + TROWS <= N) {
            for (int i = tid; i < nvec; i += 256) ((float4*)xs)[i] = x4[i];
        } else {
            for (int i = tid; i < nvec; i += 256) {
                int r = i >> 3;               // i/(HDIM/4)
                ((float4*)xs)[i] = (row0 + r < N) ? x4[i] : make_float4(0,0,0,0);
            }
        }
        __syncthreads();
        float acc[8];
        #pragma unroll
        for (int r = 0; r < 8; r++) acc[r] = 0.f;
        const int rbase = rg * 8;
        for (int k = 0; k < HDIM; k += 4) {
            float w0 = Ws[(k+0)*HDIM + col];
            float w1 = Ws[(k+1)*HDIM + col];
            float w2 = Ws[(k+2)*HDIM + col];
            float w3 = Ws[(k+3)*HDIM + col];
            #pragma unroll
            for (int r = 0; r < 8; r++) {
                float4 xv = *(const float4*)&xs[rbase + r][k];
                acc[r] += xv.x*w0 + xv.y*w1 + xv.z*w2 + xv.w*w3;
            }
        }
        #pragma unroll
        for (int r = 0; r < 8; r++) {
            int row = row0 + rbase + r;
            float ps = acc[r] * as_c, pd = acc[r] * ad_c;
            #pragma unroll
            for (int m = 16; m >= 1; m >>= 1) { ps += __shfl_xor(ps, m); pd += __shfl_xor(pd, m); }
            if (row < N) {
                h[(size_t)row * HDIM + col] = __float2half(acc[r]);
                if (col == 0) { es[row] = ps; ed[row] = pd; }
            }
        }
    }
}

// ---------------- Two-level CSR build (once per call) ----------------

__global__ __launch_bounds__(256) void chunk_hist(
    const int* __restrict__ dsts, int E, int B, int* __restrict__ cnt2D)
{
    __shared__ int hist[MAXB];
    const int blk = blockIdx.x;
    for (int i = threadIdx.x; i < B; i += 256) hist[i] = 0;
    __syncthreads();
    const int e0 = blk * CHUNK;
    for (int i = threadIdx.x; i < CHUNK; i += 256) {
        int e = e0 + i;
        if (e < E) atomicAdd(&hist[dsts[e] >> NPB_SHIFT], 1);
    }
    __syncthreads();
    for (int i = threadIdx.x; i < B; i += 256) cnt2D[(size_t)blk * B + i] = hist[i];
}

__global__ __launch_bounds__(256) void chunk_scan(
    const int* __restrict__ cnt2D, int NBLK, int B,
    int* __restrict__ off2D, int* __restrict__ bcnt)
{
    __shared__ int s[256];
    const int b = blockIdx.x, t = threadIdx.x;
    int v = (t < NBLK) ? cnt2D[(size_t)t * B + b] : 0;
    s[t] = v;
    __syncthreads();
    for (int off = 1; off < 256; off <<= 1) {
        int add = (t >= off) ? s[t - off] : 0;
        __syncthreads();
        s[t] += add;
        __syncthreads();
    }
    if (t < NBLK) off2D[(size_t)t * B + b] = s[t] - v;
    if (t == 255) bcnt[b] = s[255];
}

__global__ __launch_bounds__(1024) void bucket_scan(
    const int* __restrict__ bcnt, int B, int E,
    int* __restrict__ bstart, int* __restrict__ rowptr, int N)
{
    __shared__ int s[1024];
    const int t = threadIdx.x;
    int v = (t < B) ? bcnt[t] : 0;
    s[t] = v;
    __syncthreads();
    for (int off = 1; off < 1024; off <<= 1) {
        int add = (t >= off) ? s[t - off] : 0;
        __syncthreads();
        s[t] += add;
        __syncthreads();
    }
    if (t < B) bstart[t] = s[t] - v;
    if (t == 0) { bstart[B] = E; rowptr[N] = E; }
}

__global__ __launch_bounds__(256) void pair_scatter2(
    const int* __restrict__ srcs, const int* __restrict__ dsts, int E, int B,
    const int* __restrict__ off2D, const int* __restrict__ bstart,
    int* __restrict__ pairs)
{
    __shared__ int cur[MAXB];
    const int blk = blockIdx.x;
    for (int i = threadIdx.x; i < B; i += 256)
        cur[i] = bstart[i] + off2D[(size_t)blk * B + i];
    __syncthreads();
    const int e0 = blk * CHUNK;
    for (int i = threadIdx.x; i < CHUNK; i += 256) {
        int e = e0 + i;
        if (e < E) {
            int s = srcs[e], d = dsts[e];
            int pos = atomicAdd(&cur[d >> NPB_SHIFT], 1);
            pairs[pos] = (s << NPB_SHIFT) | (d & (NPB - 1));
        }
    }
}

__global__ __launch_bounds__(256) void bucket_sort(
    const int* __restrict__ pairs, const int* __restrict__ bstart,
    int* __restrict__ rowptr, int* __restrict__ csrsrc, int N)
{
    __shared__ int ldeg[NPB];
    __shared__ int lex[NPB];
    __shared__ int recs[CAP];
    __shared__ int sorted[CAP];
    const int b = blockIdx.x, t = threadIdx.x;
    const int p0 = bstart[b], p1 = bstart[b + 1];
    const int cnt = p1 - p0;
    if (t < NPB) ldeg[t] = 0;
    __syncthreads();
    for (int i = t; i < cnt; i += 256) {
        int r = pairs[p0 + i];
        atomicAdd(&ldeg[r & (NPB - 1)], 1);
        if (i < CAP) recs[i] = r;
    }
    __syncthreads();
    if (t < NPB) lex[t] = ldeg[t];
    __syncthreads();
    for (int off = 1; off < NPB; off <<= 1) {
        int add = (t >= off && t < NPB) ? lex[t - off] : 0;
        __syncthreads();
        if (t < NPB) lex[t] += add;
        __syncthreads();
    }
    const int node0 = b * NPB;
    if (t < NPB) {
        int excl = lex[t] - ldeg[t];
        if (node0 + t < N) rowptr[node0 + t] = p0 + excl;
        ldeg[t] = excl;
    }
    __syncthreads();
    if (cnt <= CAP) {
        for (int i = t; i < cnt; i += 256) {
            int r = recs[i];
            int pos = atomicAdd(&ldeg[r & (NPB - 1)], 1);
            sorted[pos] = r >> NPB_SHIFT;
        }
        __syncthreads();
        for (int i = t; i < cnt; i += 256) csrsrc[p0 + i] = sorted[i];
    } else {
        for (int i = t; i < cnt; i += 256) {
            int r = pairs[p0 + i];
            int pos = atomicAdd(&ldeg[r & (NPB - 1)], 1);
            csrsrc[p0 + pos] = r >> NPB_SHIFT;
        }
    }
}

// -------- Aggregation: 4 lanes/node, dwordx4 fp16 gather, 4-edge unroll ----

__global__ __launch_bounds__(256) void agg4(
    const __half* __restrict__ h, const float* __restrict__ es, const float* __restrict__ ed,
    const int* __restrict__ rowptr, const int* __restrict__ csrsrc,
    const float* __restrict__ b, float* __restrict__ out, int N)
{
    const int gid  = blockIdx.x * 256 + threadIdx.x;
    const int node = gid >> 2;
    const int l    = threadIdx.x & 3;
    if (node >= N) return;

    const int e0 = rowptr[node];
    const int e1 = rowptr[node + 1];
    const float edi = ed[node];
    const uint4* __restrict__ h16 = (const uint4*)h;   // row = 4 uint4 of 8 halves

    Acc8 A; A.init();
    float den = 0.f;

    int e = e0;
    for (; e + 4 <= e1; e += 4) {
        int s0 = csrsrc[e], s1 = csrsrc[e+1], s2 = csrsrc[e+2], s3 = csrsrc[e+3];
        float q0 = es[s0], q1 = es[s1], q2 = es[s2], q3 = es[s3];
        uint4 u0 = h16[(size_t)s0*4 + l];
        uint4 u1 = h16[(size_t)s1*4 + l];
        uint4 u2 = h16[(size_t)s2*4 + l];
        uint4 u3 = h16[(size_t)s3*4 + l];
        float w0 = __expf(leaky(q0 + edi));
        float w1 = __expf(leaky(q1 + edi));
        float w2 = __expf(leaky(q2 + edi));
        float w3 = __expf(leaky(q3 + edi));
        den += w0 + w1 + w2 + w3;
        A.fma(u0, w0); A.fma(u1, w1); A.fma(u2, w2); A.fma(u3, w3);
    }
    for (; e < e1; e++) {
        int s = csrsrc[e];
        float wt = __expf(leaky(es[s] + edi));
        uint4 u = h16[(size_t)s*4 + l];
        den += wt;
        A.fma(u, wt);
    }
    {   // self-loop
        float wt = __expf(leaky(es[node] + edi));
        uint4 u = h16[(size_t)node*4 + l];
        den += wt;
        A.fma(u, wt);
    }
    const float4* b4 = (const float4*)b;
    float4 bv0 = b4[2*l], bv1 = b4[2*l + 1];
    float inv = 1.f / den;
    float4 o0, o1;
    o0.x = A.a0*inv + bv0.x; o0.y = A.a1*inv + bv0.y; o0.z = A.a2*inv + bv0.z; o0.w = A.a3*inv + bv0.w;
    o1.x = A.a4*inv + bv1.x; o1.y = A.a5*inv + bv1.y; o1.z = A.a6*inv + bv1.z; o1.w = A.a7*inv + bv1.w;
    ((float4*)out)[(size_t)node*8 + 2*l]     = o0;
    ((float4*)out)[(size_t)node*8 + 2*l + 1] = o1;
}

// ---------------- Pool: run-length accumulation (batch is sorted) ---------

#define PNPG 128   // nodes per 32-lane group

__global__ __launch_bounds__(256) void pool_rle(
    const float* __restrict__ x, const int* __restrict__ batch,
    float* __restrict__ psum, float* __restrict__ pcnt, int N)
{
    const int grp  = (blockIdx.x * 256 + threadIdx.x) >> 5;
    const int lane = threadIdx.x & 31;
    const int n0 = grp * PNPG;
    if (n0 >= N) return;
    const int n1 = (n0 + PNPG < N) ? n0 + PNPG : N;

    int gcur = batch[n0];
    float acc = 0.f, cnt = 0.f;
    for (int i = n0; i < n1; i++) {
        int g = batch[i];
        if (g != gcur) {
            atomicAdd(&psum[(size_t)gcur * HDIM + lane], acc);
            if (lane == 0) atomicAdd(&pcnt[gcur], cnt);
            acc = 0.f; cnt = 0.f; gcur = g;
        }
        acc += x[(size_t)i * HDIM + lane];
        cnt += 1.f;
    }
    atomicAdd(&psum[(size_t)gcur * HDIM + lane], acc);
    if (lane == 0) atomicAdd(&pcnt[gcur], cnt);
}

__global__ __launch_bounds__(256) void pool_div(
    const float* __restrict__ psum, const float* __restrict__ pcnt,
    float* __restrict__ out, int G)
{
    int t = blockIdx.x * blockDim.x + threadIdx.x;
    if (t >= G * HDIM) return;
    int g = t >> 5;
    out[t] = psum[t] / fmaxf(pcnt[g], 1.f);
}

// ---------------- Launch ----------------

extern "C" void kernel_launch(void* const* d_in, const int* in_sizes, int n_in,
                              void* d_out, int out_size, void* d_ws, size_t ws_size,
                              hipStream_t stream) {
    const float* x          = (const float*)d_in[0];
    const int*   edge_index = (const int*)d_in[1];
    const int*   batch      = (const int*)d_in[2];

    const int N = in_sizes[2];              // 100000
    const int E = in_sizes[1] / 2;          // 1600000
    const int G = out_size / HDIM;          // 2048
    const int B = (N + NPB - 1) / NPB;      // 782 buckets
    const int NBLK = (E + CHUNK - 1) / CHUNK;
    const int ntiles = (N + TROWS - 1) / TROWS;

    const int* srcs = edge_index;
    const int* dsts = edge_index + E;

    // workspace layout (float4-accessed buffers first, 16B-aligned offsets)
    char* p = (char*)d_ws;
    __half* h     = (__half*)p; p += (size_t)N * HDIM * sizeof(__half);
    float* xbuf   = (float*)p; p += (size_t)N * HDIM * sizeof(float);
    float* es     = (float*)p; p += (size_t)N * sizeof(float);
    float* ed     = (float*)p; p += (size_t)N * sizeof(float);
    int*   rowptr = (int*)p;   p += (size_t)(N + 1) * sizeof(int);
    int*   csrsrc = (int*)p;   p += (size_t)E * sizeof(int);
    int*   pairs  = (int*)p;   p += (size_t)E * sizeof(int);
    int*   cnt2D  = (int*)p;   p += (size_t)NBLK * B * sizeof(int);
    int*   off2D  = (int*)p;   p += (size_t)NBLK * B * sizeof(int);
    int*   bcnt   = (int*)p;   p += (size_t)B * sizeof(int);
    int*   bstart = (int*)p;   p += (size_t)(B + 1) * sizeof(int);
    float* psum   = (float*)p; p += (size_t)G * HDIM * sizeof(float);
    float* pcnt   = (float*)p; p += (size_t)G * sizeof(float);

    // ---- CSR build (once; same edge set for all 4 layers) ----
    chunk_hist  <<<NBLK, 256, 0, stream>>>(dsts, E, B, cnt2D);
    chunk_scan  <<<B, 256, 0, stream>>>(cnt2D, NBLK, B, off2D, bcnt);
    bucket_scan <<<1, 1024, 0, stream>>>(bcnt, B, E, bstart, rowptr, N);
    pair_scatter2<<<NBLK, 256, 0, stream>>>(srcs, dsts, E, B, off2D, bstart, pairs);
    bucket_sort <<<B, 256, 0, stream>>>(pairs, bstart, rowptr, csrsrc, N);

    // ---- 4 GAT layers ----
    for (int l = 0; l < 4; l++) {
        const float* W   = (const float*)d_in[3 + 4 * l];
        const float* a_s = (const float*)d_in[4 + 4 * l];
        const float* a_d = (const float*)d_in[5 + 4 * l];
        const float* bb  = (const float*)d_in[6 + 4 * l];

        if (l == 0) gemm128<<<ntiles, 256, 0, stream>>>(x, W, a_s, a_d, h, es, ed, N);
        else        gemm32 <<<ntiles, 256, 0, stream>>>(xbuf, W, a_s, a_d, h, es, ed, N);

        agg4<<<(N * 4 + 255) / 256, 256, 0, stream>>>(h, es, ed, rowptr, csrsrc, bb, xbuf, N);
    }

    // ---- global mean pool ----
    hipMemsetAsync(psum, 0, (size_t)(G * HDIM + G) * sizeof(float), stream);
    pool_rle<<<((N + PNPG - 1) / PNPG * 32 + 255) / 256, 256, 0, stream>>>(xbuf, batch, psum, pcnt, N);
    pool_div<<<(G * HDIM + 255) / 256, 256, 0, stream>>>(psum, pcnt, (float*)d_out, G);
}

// Round 8
// 452.525 us; speedup vs baseline: 1.0355x; 1.0355x over previous
//
#include <hip/hip_runtime.h>
#include <hip/hip_fp16.h>

#define HDIM 32
#define IN_DIM 128
#define NEG_SLOPE 0.2f
#define NPB 128            // nodes per coarse bucket (power of 2)
#define NPB_SHIFT 7
#define MAXB 1024          // max buckets (B = ceil(N/128) = 782)
#define CHUNK 8192         // edges per chunk block
#define CAP 4096           // max records per bucket for LDS sort fast path
#define TROWS 64           // GEMM tile rows

__device__ __forceinline__ float leaky(float e) {
    return (e >= 0.f) ? e : NEG_SLOPE * e;
}

__device__ __forceinline__ float2 h2f(unsigned int u) {
    __half2 h = *reinterpret_cast<__half2*>(&u);
    return __half22float2(h);
}

struct Acc8 {
    float a0, a1, a2, a3, a4, a5, a6, a7;
    __device__ __forceinline__ void init() { a0=a1=a2=a3=a4=a5=a6=a7=0.f; }
    __device__ __forceinline__ void fma(uint4 u, float wt) {
        float2 f0 = h2f(u.x), f1 = h2f(u.y), f2 = h2f(u.z), f3 = h2f(u.w);
        a0 += wt * f0.x; a1 += wt * f0.y; a2 += wt * f1.x; a3 += wt * f1.y;
        a4 += wt * f2.x; a5 += wt * f2.y; a6 += wt * f3.x; a7 += wt * f3.y;
    }
};

// ---------------- GEMM kernels: 64-row tile, 8 outputs/thread -------------

__global__ __launch_bounds__(256) void gemm128(
    const float* __restrict__ x, const float* __restrict__ W,
    const float* __restrict__ a_s, const float* __restrict__ a_d,
    __half* __restrict__ h, float* __restrict__ es, float* __restrict__ ed, int N)
{
    __shared__ float Ws[IN_DIM * HDIM];      // 16 KB, [k][col]
    __shared__ float xs[TROWS][IN_DIM];      // 32 KB
    const int tid = threadIdx.x;
    for (int i = tid; i < IN_DIM * HDIM; i += 256) Ws[i] = W[i];
    const int col = tid & 31;
    const int rg  = tid >> 5;                // 0..7 -> rows rg*8..rg*8+7
    const float as_c = a_s[col], ad_c = a_d[col];
    const int ntiles = (N + TROWS - 1) / TROWS;
    for (int tile = blockIdx.x; tile < ntiles; tile += gridDim.x) {
        const int row0 = tile * TROWS;
        __syncthreads();
        const float4* x4 = (const float4*)(x + (size_t)row0 * IN_DIM);
        const int nvec = TROWS * IN_DIM / 4;  // 2048
        if (row0 + TROWS <= N) {
            for (int i = tid; i < nvec; i += 256) ((float4*)xs)[i] = x4[i];
        } else {
            for (int i = tid; i < nvec; i += 256) {
                int r = i >> 5;               // i/(IN_DIM/4)
                ((float4*)xs)[i] = (row0 + r < N) ? x4[i] : make_float4(0,0,0,0);
            }
        }
        __syncthreads();
        float acc[8];
        #pragma unroll
        for (int r = 0; r < 8; r++) acc[r] = 0.f;
        const int rbase = rg * 8;
        for (int k = 0; k < IN_DIM; k += 4) {
            float w0 = Ws[(k+0)*HDIM + col];
            float w1 = Ws[(k+1)*HDIM + col];
            float w2 = Ws[(k+2)*HDIM + col];
            float w3 = Ws[(k+3)*HDIM + col];
            #pragma unroll
            for (int r = 0; r < 8; r++) {
                float4 xv = *(const float4*)&xs[rbase + r][k];
                acc[r] += xv.x*w0 + xv.y*w1 + xv.z*w2 + xv.w*w3;
            }
        }
        #pragma unroll
        for (int r = 0; r < 8; r++) {
            int row = row0 + rbase + r;
            float ps = acc[r] * as_c, pd = acc[r] * ad_c;
            #pragma unroll
            for (int m = 16; m >= 1; m >>= 1) { ps += __shfl_xor(ps, m); pd += __shfl_xor(pd, m); }
            if (row < N) {
                h[(size_t)row * HDIM + col] = __float2half(acc[r]);
                if (col == 0) { es[row] = ps; ed[row] = pd; }
            }
        }
    }
}

__global__ __launch_bounds__(256) void gemm32(
    const float* __restrict__ x, const float* __restrict__ W,
    const float* __restrict__ a_s, const float* __restrict__ a_d,
    __half* __restrict__ h, float* __restrict__ es, float* __restrict__ ed, int N)
{
    __shared__ float Ws[HDIM * HDIM];        // 4 KB
    __shared__ float xs[TROWS][HDIM];        // 8 KB
    const int tid = threadIdx.x;
    for (int i = tid; i < HDIM * HDIM; i += 256) Ws[i] = W[i];
    const int col = tid & 31;
    const int rg  = tid >> 5;
    const float as_c = a_s[col], ad_c = a_d[col];
    const int ntiles = (N + TROWS - 1) / TROWS;
    for (int tile = blockIdx.x; tile < ntiles; tile += gridDim.x) {
        const int row0 = tile * TROWS;
        __syncthreads();
        const float4* x4 = (const float4*)(x + (size_t)row0 * HDIM);
        const int nvec = TROWS * HDIM / 4;   // 512
        if (row0 + TROWS <= N) {
            for (int i = tid; i < nvec; i += 256) ((float4*)xs)[i] = x4[i];
        } else {
            for (int i = tid; i < nvec; i += 256) {
                int r = i >> 3;               // i/(HDIM/4)
                ((float4*)xs)[i] = (row0 + r < N) ? x4[i] : make_float4(0,0,0,0);
            }
        }
        __syncthreads();
        float acc[8];
        #pragma unroll
        for (int r = 0; r < 8; r++) acc[r] = 0.f;
        const int rbase = rg * 8;
        for (int k = 0; k < HDIM; k += 4) {
            float w0 = Ws[(k+0)*HDIM + col];
            float w1 = Ws[(k+1)*HDIM + col];
            float w2 = Ws[(k+2)*HDIM + col];
            float w3 = Ws[(k+3)*HDIM + col];
            #pragma unroll
            for (int r = 0; r < 8; r++) {
                float4 xv = *(const float4*)&xs[rbase + r][k];
                acc[r] += xv.x*w0 + xv.y*w1 + xv.z*w2 + xv.w*w3;
            }
        }
        #pragma unroll
        for (int r = 0; r < 8; r++) {
            int row = row0 + rbase + r;
            float ps = acc[r] * as_c, pd = acc[r] * ad_c;
            #pragma unroll
            for (int m = 16; m >= 1; m >>= 1) { ps += __shfl_xor(ps, m); pd += __shfl_xor(pd, m); }
            if (row < N) {
                h[(size_t)row * HDIM + col] = __float2half(acc[r]);
                if (col == 0) { es[row] = ps; ed[row] = pd; }
            }
        }
    }
}

// ---------------- Two-level CSR build (once per call) ----------------

__global__ __launch_bounds__(256) void chunk_hist(
    const int* __restrict__ dsts, int E, int B, int* __restrict__ cnt2D)
{
    __shared__ int hist[MAXB];
    const int blk = blockIdx.x;
    for (int i = threadIdx.x; i < B; i += 256) hist[i] = 0;
    __syncthreads();
    const int e0 = blk * CHUNK;
    for (int i = threadIdx.x; i < CHUNK; i += 256) {
        int e = e0 + i;
        if (e < E) atomicAdd(&hist[dsts[e] >> NPB_SHIFT], 1);
    }
    __syncthreads();
    for (int i = threadIdx.x; i < B; i += 256) cnt2D[(size_t)blk * B + i] = hist[i];
}

__global__ __launch_bounds__(256) void chunk_scan(
    const int* __restrict__ cnt2D, int NBLK, int B,
    int* __restrict__ off2D, int* __restrict__ bcnt)
{
    __shared__ int s[256];
    const int b = blockIdx.x, t = threadIdx.x;
    int v = (t < NBLK) ? cnt2D[(size_t)t * B + b] : 0;
    s[t] = v;
    __syncthreads();
    for (int off = 1; off < 256; off <<= 1) {
        int add = (t >= off) ? s[t - off] : 0;
        __syncthreads();
        s[t] += add;
        __syncthreads();
    }
    if (t < NBLK) off2D[(size_t)t * B + b] = s[t] - v;
    if (t == 255) bcnt[b] = s[255];
}

__global__ __launch_bounds__(1024) void bucket_scan(
    const int* __restrict__ bcnt, int B, int E,
    int* __restrict__ bstart, int* __restrict__ rowptr, int N)
{
    __shared__ int s[1024];
    const int t = threadIdx.x;
    int v = (t < B) ? bcnt[t] : 0;
    s[t] = v;
    __syncthreads();
    for (int off = 1; off < 1024; off <<= 1) {
        int add = (t >= off) ? s[t - off] : 0;
        __syncthreads();
        s[t] += add;
        __syncthreads();
    }
    if (t < B) bstart[t] = s[t] - v;
    if (t == 0) { bstart[B] = E; rowptr[N] = E; }
}

__global__ __launch_bounds__(256) void pair_scatter2(
    const int* __restrict__ srcs, const int* __restrict__ dsts, int E, int B,
    const int* __restrict__ off2D, const int* __restrict__ bstart,
    int* __restrict__ pairs)
{
    __shared__ int cur[MAXB];
    const int blk = blockIdx.x;
    for (int i = threadIdx.x; i < B; i += 256)
        cur[i] = bstart[i] + off2D[(size_t)blk * B + i];
    __syncthreads();
    const int e0 = blk * CHUNK;
    for (int i = threadIdx.x; i < CHUNK; i += 256) {
        int e = e0 + i;
        if (e < E) {
            int s = srcs[e], d = dsts[e];
            int pos = atomicAdd(&cur[d >> NPB_SHIFT], 1);
            pairs[pos] = (s << NPB_SHIFT) | (d & (NPB - 1));
        }
    }
}

__global__ __launch_bounds__(256) void bucket_sort(
    const int* __restrict__ pairs, const int* __restrict__ bstart,
    int* __restrict__ rowptr, int* __restrict__ csrsrc, int N)
{
    __shared__ int ldeg[NPB];
    __shared__ int lex[NPB];
    __shared__ int recs[CAP];
    __shared__ int sorted[CAP];
    const int b = blockIdx.x, t = threadIdx.x;
    const int p0 = bstart[b], p1 = bstart[b + 1];
    const int cnt = p1 - p0;
    if (t < NPB) ldeg[t] = 0;
    __syncthreads();
    for (int i = t; i < cnt; i += 256) {
        int r = pairs[p0 + i];
        atomicAdd(&ldeg[r & (NPB - 1)], 1);
        if (i < CAP) recs[i] = r;
    }
    __syncthreads();
    if (t < NPB) lex[t] = ldeg[t];
    __syncthreads();
    for (int off = 1; off < NPB; off <<= 1) {
        int add = (t >= off && t < NPB) ? lex[t - off] : 0;
        __syncthreads();
        if (t < NPB) lex[t] += add;
        __syncthreads();
    }
    const int node0 = b * NPB;
    if (t < NPB) {
        int excl = lex[t] - ldeg[t];
        if (node0 + t < N) rowptr[node0 + t] = p0 + excl;
        ldeg[t] = excl;
    }
    __syncthreads();
    if (cnt <= CAP) {
        for (int i = t; i < cnt; i += 256) {
            int r = recs[i];
            int pos = atomicAdd(&ldeg[r & (NPB - 1)], 1);
            sorted[pos] = r >> NPB_SHIFT;
        }
        __syncthreads();
        for (int i = t; i < cnt; i += 256) csrsrc[p0 + i] = sorted[i];
    } else {
        for (int i = t; i < cnt; i += 256) {
            int r = pairs[p0 + i];
            int pos = atomicAdd(&ldeg[r & (NPB - 1)], 1);
            csrsrc[p0 + pos] = r >> NPB_SHIFT;
        }
    }
}

// -------- Aggregation: 4 lanes/node, dwordx4 fp16 gather, 8-edge unroll ----

__global__ __launch_bounds__(256) void agg4(
    const __half* __restrict__ h, const float* __restrict__ es, const float* __restrict__ ed,
    const int* __restrict__ rowptr, const int* __restrict__ csrsrc,
    const float* __restrict__ b, float* __restrict__ out, int N)
{
    const int gid  = blockIdx.x * 256 + threadIdx.x;
    const int node = gid >> 2;
    const int l    = threadIdx.x & 3;
    if (node >= N) return;

    const int e0 = rowptr[node];
    const int e1 = rowptr[node + 1];
    const float edi = ed[node];
    const uint4* __restrict__ h16 = (const uint4*)h;   // row = 4 uint4 of 8 halves

    Acc8 A; A.init();
    float den = 0.f;

    int e = e0;
    for (; e + 8 <= e1; e += 8) {
        int s[8]; float q[8]; uint4 u[8]; float w[8];
        #pragma unroll
        for (int j = 0; j < 8; j++) s[j] = csrsrc[e + j];
        #pragma unroll
        for (int j = 0; j < 8; j++) q[j] = es[s[j]];
        #pragma unroll
        for (int j = 0; j < 8; j++) u[j] = h16[(size_t)s[j] * 4 + l];
        #pragma unroll
        for (int j = 0; j < 8; j++) w[j] = __expf(leaky(q[j] + edi));
        #pragma unroll
        for (int j = 0; j < 8; j++) { den += w[j]; A.fma(u[j], w[j]); }
    }
    for (; e < e1; e++) {
        int s = csrsrc[e];
        float wt = __expf(leaky(es[s] + edi));
        uint4 u = h16[(size_t)s * 4 + l];
        den += wt;
        A.fma(u, wt);
    }
    {   // self-loop
        float wt = __expf(leaky(es[node] + edi));
        uint4 u = h16[(size_t)node * 4 + l];
        den += wt;
        A.fma(u, wt);
    }
    const float4* b4 = (const float4*)b;
    float4 bv0 = b4[2*l], bv1 = b4[2*l + 1];
    float inv = 1.f / den;
    float4 o0, o1;
    o0.x = A.a0*inv + bv0.x; o0.y = A.a1*inv + bv0.y; o0.z = A.a2*inv + bv0.z; o0.w = A.a3*inv + bv0.w;
    o1.x = A.a4*inv + bv1.x; o1.y = A.a5*inv + bv1.y; o1.z = A.a6*inv + bv1.z; o1.w = A.a7*inv + bv1.w;
    ((float4*)out)[(size_t)node*8 + 2*l]     = o0;
    ((float4*)out)[(size_t)node*8 + 2*l + 1] = o1;
}

// -------- Pool: one 64-lane wave per graph (batch sorted, binary search) ---

__global__ __launch_bounds__(256) void pool_graph(
    const float* __restrict__ x, const int* __restrict__ batch,
    float* __restrict__ out, int N, int G)
{
    const int g = (blockIdx.x * 256 + threadIdx.x) >> 6;   // wave id = graph id
    if (g >= G) return;
    const int lane = threadIdx.x & 63;
    const int feat = lane & 31;
    const int half = lane >> 5;

    // start = lower_bound(batch, g); end = lower_bound(batch, g+1)
    int lo = 0, hi = N;
    while (lo < hi) { int mid = (lo + hi) >> 1; if (batch[mid] < g) lo = mid + 1; else hi = mid; }
    const int start = lo;
    int lo2 = start, hi2 = N;
    while (lo2 < hi2) { int mid = (lo2 + hi2) >> 1; if (batch[mid] < g + 1) lo2 = mid + 1; else hi2 = mid; }
    const int end = lo2;

    float acc = 0.f;
    for (int i = start + half; i < end; i += 2)
        acc += x[(size_t)i * HDIM + feat];
    acc += __shfl_xor(acc, 32);
    if (half == 0) {
        float cnt = (float)(end - start);
        out[(size_t)g * HDIM + feat] = acc / fmaxf(cnt, 1.f);
    }
}

// ---------------- Launch ----------------

extern "C" void kernel_launch(void* const* d_in, const int* in_sizes, int n_in,
                              void* d_out, int out_size, void* d_ws, size_t ws_size,
                              hipStream_t stream) {
    const float* x          = (const float*)d_in[0];
    const int*   edge_index = (const int*)d_in[1];
    const int*   batch      = (const int*)d_in[2];

    const int N = in_sizes[2];              // 100000
    const int E = in_sizes[1] / 2;          // 1600000
    const int G = out_size / HDIM;          // 2048
    const int B = (N + NPB - 1) / NPB;      // 782 buckets
    const int NBLK = (E + CHUNK - 1) / CHUNK;
    const int ntiles = (N + TROWS - 1) / TROWS;

    const int* srcs = edge_index;
    const int* dsts = edge_index + E;

    // workspace layout (float4-accessed buffers first, 16B-aligned offsets)
    char* p = (char*)d_ws;
    __half* h     = (__half*)p; p += (size_t)N * HDIM * sizeof(__half);
    float* xbuf   = (float*)p; p += (size_t)N * HDIM * sizeof(float);
    float* es     = (float*)p; p += (size_t)N * sizeof(float);
    float* ed     = (float*)p; p += (size_t)N * sizeof(float);
    int*   rowptr = (int*)p;   p += (size_t)(N + 1) * sizeof(int);
    int*   csrsrc = (int*)p;   p += (size_t)E * sizeof(int);
    int*   pairs  = (int*)p;   p += (size_t)E * sizeof(int);
    int*   cnt2D  = (int*)p;   p += (size_t)NBLK * B * sizeof(int);
    int*   off2D  = (int*)p;   p += (size_t)NBLK * B * sizeof(int);
    int*   bcnt   = (int*)p;   p += (size_t)B * sizeof(int);
    int*   bstart = (int*)p;   p += (size_t)(B + 1) * sizeof(int);

    // ---- CSR build (once; same edge set for all 4 layers) ----
    chunk_hist  <<<NBLK, 256, 0, stream>>>(dsts, E, B, cnt2D);
    chunk_scan  <<<B, 256, 0, stream>>>(cnt2D, NBLK, B, off2D, bcnt);
    bucket_scan <<<1, 1024, 0, stream>>>(bcnt, B, E, bstart, rowptr, N);
    pair_scatter2<<<NBLK, 256, 0, stream>>>(srcs, dsts, E, B, off2D, bstart, pairs);
    bucket_sort <<<B, 256, 0, stream>>>(pairs, bstart, rowptr, csrsrc, N);

    // ---- 4 GAT layers ----
    for (int l = 0; l < 4; l++) {
        const float* W   = (const float*)d_in[3 + 4 * l];
        const float* a_s = (const float*)d_in[4 + 4 * l];
        const float* a_d = (const float*)d_in[5 + 4 * l];
        const float* bb  = (const float*)d_in[6 + 4 * l];

        if (l == 0) gemm128<<<ntiles, 256, 0, stream>>>(x, W, a_s, a_d, h, es, ed, N);
        else        gemm32 <<<ntiles, 256, 0, stream>>>(xbuf, W, a_s, a_d, h, es, ed, N);

        agg4<<<(N * 4 + 255) / 256, 256, 0, stream>>>(h, es, ed, rowptr, csrsrc, bb, xbuf, N);
    }

    // ---- global mean pool: one wave per graph ----
    pool_graph<<<(G * 64 + 255) / 256, 256, 0, stream>>>(xbuf, batch, (float*)d_out, N, G);
}

// Round 9
// 353.698 us; speedup vs baseline: 1.3249x; 1.2794x over previous
//
#include <hip/hip_runtime.h>
#include <hip/hip_fp16.h>

#define HDIM 32
#define IN_DIM 128
#define NEG_SLOPE 0.2f
#define NPB 128            // nodes per coarse bucket (power of 2)
#define NPB_SHIFT 7
#define MAXB 1024          // max buckets (B = ceil(N/128) = 782)
#define CHUNK 8192         // edges per chunk block
#define CAP 4096           // max records per bucket for LDS sort fast path

typedef _Float16 half8  __attribute__((ext_vector_type(8)));
typedef _Float16 half4v __attribute__((ext_vector_type(4)));
typedef float    floatx4 __attribute__((ext_vector_type(4)));

__device__ __forceinline__ float leaky(float e) {
    return (e >= 0.f) ? e : NEG_SLOPE * e;
}

__device__ __forceinline__ float2 h2f(unsigned int u) {
    __half2 h = *reinterpret_cast<__half2*>(&u);
    return __half22float2(h);
}

struct Acc8 {
    float a0, a1, a2, a3, a4, a5, a6, a7;
    __device__ __forceinline__ void init() { a0=a1=a2=a3=a4=a5=a6=a7=0.f; }
    __device__ __forceinline__ void fma(uint4 u, float wt) {
        float2 f0 = h2f(u.x), f1 = h2f(u.y), f2 = h2f(u.z), f3 = h2f(u.w);
        a0 += wt * f0.x; a1 += wt * f0.y; a2 += wt * f1.x; a3 += wt * f1.y;
        a4 += wt * f2.x; a5 += wt * f2.y; a6 += wt * f3.x; a7 += wt * f3.y;
    }
};

// ------------- MFMA GEMM: h = x@W (fp16 in, fp32 acc), es/ed fused ---------
// Per block: 64 rows, 4 waves; per wave: 16 rows x 32 cols.
// Layouts (guide §3, 16x16x32): A[m=lane&15][k=quad*8+j], B[n=lane&15][k=quad*8+j],
// C: col=lane&15 (+16 for second tile), row=quad*4+reg.

template<int K>
__global__ __launch_bounds__(256) void gemm_mfma(
    const float* __restrict__ x, const float* __restrict__ W,
    const float* __restrict__ a_s, const float* __restrict__ a_d,
    __half* __restrict__ h, float* __restrict__ es, float* __restrict__ ed, int N)
{
    constexpr int KP = K + 8;                 // +8 halves pad -> 2-way conflicts only
    __shared__ _Float16 xs[64 * KP];
    __shared__ _Float16 Wt[32 * KP];          // Wt[n][k] = W[k][n]
    const int tid = threadIdx.x;
    for (int i = tid; i < K * 32; i += 256) {
        int k = i >> 5, n = i & 31;
        Wt[n * KP + k] = (_Float16)W[i];
    }
    const int lane = tid & 63;
    const int wave = tid >> 6;                // 0..3
    const int m16  = lane & 15;
    const int quad = lane >> 4;               // 0..3
    const float as0 = a_s[m16], as1 = a_s[m16 + 16];
    const float ad0 = a_d[m16], ad1 = a_d[m16 + 16];

    const int ntiles = (N + 63) >> 6;
    for (int tile = blockIdx.x; tile < ntiles; tile += gridDim.x) {
        const int row0 = tile << 6;
        __syncthreads();
        for (int i = tid; i < 64 * (K / 4); i += 256) {
            int r  = i / (K / 4);
            int c4 = i % (K / 4);
            float4 v = (row0 + r < N) ? ((const float4*)x)[(size_t)(row0 + r) * (K / 4) + c4]
                                      : make_float4(0.f, 0.f, 0.f, 0.f);
            half4v hv = { (_Float16)v.x, (_Float16)v.y, (_Float16)v.z, (_Float16)v.w };
            *(half4v*)&xs[r * KP + c4 * 4] = hv;
        }
        __syncthreads();
        floatx4 acc0 = {0.f, 0.f, 0.f, 0.f}, acc1 = {0.f, 0.f, 0.f, 0.f};
        const int rbase = wave * 16;
        #pragma unroll
        for (int kt = 0; kt < K / 32; kt++) {
            half8 a  = *(half8*)&xs[(rbase + m16) * KP + kt * 32 + quad * 8];
            half8 b0 = *(half8*)&Wt[m16 * KP + kt * 32 + quad * 8];
            half8 b1 = *(half8*)&Wt[(m16 + 16) * KP + kt * 32 + quad * 8];
            acc0 = __builtin_amdgcn_mfma_f32_16x16x32_f16(a, b0, acc0, 0, 0, 0);
            acc1 = __builtin_amdgcn_mfma_f32_16x16x32_f16(a, b1, acc1, 0, 0, 0);
        }
        #pragma unroll
        for (int r = 0; r < 4; r++) {
            int row = row0 + rbase + quad * 4 + r;
            float c0 = acc0[r], c1 = acc1[r];
            float ps = c0 * as0 + c1 * as1;
            float pd = c0 * ad0 + c1 * ad1;
            #pragma unroll
            for (int m = 8; m >= 1; m >>= 1) { ps += __shfl_xor(ps, m); pd += __shfl_xor(pd, m); }
            if (row < N) {
                h[(size_t)row * HDIM + m16]      = __float2half(c0);
                h[(size_t)row * HDIM + m16 + 16] = __float2half(c1);
                if (m16 == 0) { es[row] = ps; ed[row] = pd; }
            }
        }
    }
}

// ---------------- Two-level CSR build (once per call) ----------------

__global__ __launch_bounds__(256) void chunk_hist(
    const int* __restrict__ dsts, int E, int B, int* __restrict__ cnt2D)
{
    __shared__ int hist[MAXB];
    const int blk = blockIdx.x;
    for (int i = threadIdx.x; i < B; i += 256) hist[i] = 0;
    __syncthreads();
    const int e0 = blk * CHUNK;
    for (int i = threadIdx.x; i < CHUNK; i += 256) {
        int e = e0 + i;
        if (e < E) atomicAdd(&hist[dsts[e] >> NPB_SHIFT], 1);
    }
    __syncthreads();
    for (int i = threadIdx.x; i < B; i += 256) cnt2D[(size_t)blk * B + i] = hist[i];
}

__global__ __launch_bounds__(256) void chunk_scan(
    const int* __restrict__ cnt2D, int NBLK, int B,
    int* __restrict__ off2D, int* __restrict__ bcnt)
{
    __shared__ int s[256];
    const int b = blockIdx.x, t = threadIdx.x;
    int v = (t < NBLK) ? cnt2D[(size_t)t * B + b] : 0;
    s[t] = v;
    __syncthreads();
    for (int off = 1; off < 256; off <<= 1) {
        int add = (t >= off) ? s[t - off] : 0;
        __syncthreads();
        s[t] += add;
        __syncthreads();
    }
    if (t < NBLK) off2D[(size_t)t * B + b] = s[t] - v;
    if (t == 255) bcnt[b] = s[255];
}

__global__ __launch_bounds__(1024) void bucket_scan(
    const int* __restrict__ bcnt, int B, int E,
    int* __restrict__ bstart, int* __restrict__ rowptr, int N)
{
    __shared__ int s[1024];
    const int t = threadIdx.x;
    int v = (t < B) ? bcnt[t] : 0;
    s[t] = v;
    __syncthreads();
    for (int off = 1; off < 1024; off <<= 1) {
        int add = (t >= off) ? s[t - off] : 0;
        __syncthreads();
        s[t] += add;
        __syncthreads();
    }
    if (t < B) bstart[t] = s[t] - v;
    if (t == 0) { bstart[B] = E; rowptr[N] = E; }
}

__global__ __launch_bounds__(256) void pair_scatter2(
    const int* __restrict__ srcs, const int* __restrict__ dsts, int E, int B,
    const int* __restrict__ off2D, const int* __restrict__ bstart,
    int* __restrict__ pairs)
{
    __shared__ int cur[MAXB];
    const int blk = blockIdx.x;
    for (int i = threadIdx.x; i < B; i += 256)
        cur[i] = bstart[i] + off2D[(size_t)blk * B + i];
    __syncthreads();
    const int e0 = blk * CHUNK;
    for (int i = threadIdx.x; i < CHUNK; i += 256) {
        int e = e0 + i;
        if (e < E) {
            int s = srcs[e], d = dsts[e];
            int pos = atomicAdd(&cur[d >> NPB_SHIFT], 1);
            pairs[pos] = (s << NPB_SHIFT) | (d & (NPB - 1));
        }
    }
}

__global__ __launch_bounds__(256) void bucket_sort(
    const int* __restrict__ pairs, const int* __restrict__ bstart,
    int* __restrict__ rowptr, int* __restrict__ csrsrc, int N)
{
    __shared__ int ldeg[NPB];
    __shared__ int lex[NPB];
    __shared__ int recs[CAP];
    __shared__ int sorted[CAP];
    const int b = blockIdx.x, t = threadIdx.x;
    const int p0 = bstart[b], p1 = bstart[b + 1];
    const int cnt = p1 - p0;
    if (t < NPB) ldeg[t] = 0;
    __syncthreads();
    for (int i = t; i < cnt; i += 256) {
        int r = pairs[p0 + i];
        atomicAdd(&ldeg[r & (NPB - 1)], 1);
        if (i < CAP) recs[i] = r;
    }
    __syncthreads();
    if (t < NPB) lex[t] = ldeg[t];
    __syncthreads();
    for (int off = 1; off < NPB; off <<= 1) {
        int add = (t >= off && t < NPB) ? lex[t - off] : 0;
        __syncthreads();
        if (t < NPB) lex[t] += add;
        __syncthreads();
    }
    const int node0 = b * NPB;
    if (t < NPB) {
        int excl = lex[t] - ldeg[t];
        if (node0 + t < N) rowptr[node0 + t] = p0 + excl;
        ldeg[t] = excl;
    }
    __syncthreads();
    if (cnt <= CAP) {
        for (int i = t; i < cnt; i += 256) {
            int r = recs[i];
            int pos = atomicAdd(&ldeg[r & (NPB - 1)], 1);
            sorted[pos] = r >> NPB_SHIFT;
        }
        __syncthreads();
        for (int i = t; i < cnt; i += 256) csrsrc[p0 + i] = sorted[i];
    } else {
        for (int i = t; i < cnt; i += 256) {
            int r = pairs[p0 + i];
            int pos = atomicAdd(&ldeg[r & (NPB - 1)], 1);
            csrsrc[p0 + pos] = r >> NPB_SHIFT;
        }
    }
}

// -------- Aggregation: 4 lanes/node, dwordx4 fp16 gather, 8-edge unroll ----

__global__ __launch_bounds__(256) void agg4(
    const __half* __restrict__ h, const float* __restrict__ es, const float* __restrict__ ed,
    const int* __restrict__ rowptr, const int* __restrict__ csrsrc,
    const float* __restrict__ b, float* __restrict__ out, int N)
{
    const int gid  = blockIdx.x * 256 + threadIdx.x;
    const int node = gid >> 2;
    const int l    = threadIdx.x & 3;
    if (node >= N) return;

    const int e0 = rowptr[node];
    const int e1 = rowptr[node + 1];
    const float edi = ed[node];
    const uint4* __restrict__ h16 = (const uint4*)h;   // row = 4 uint4 of 8 halves

    Acc8 A; A.init();
    float den = 0.f;

    int e = e0;
    for (; e + 8 <= e1; e += 8) {
        int s[8]; float q[8]; uint4 u[8]; float w[8];
        #pragma unroll
        for (int j = 0; j < 8; j++) s[j] = csrsrc[e + j];
        #pragma unroll
        for (int j = 0; j < 8; j++) q[j] = es[s[j]];
        #pragma unroll
        for (int j = 0; j < 8; j++) u[j] = h16[(size_t)s[j] * 4 + l];
        #pragma unroll
        for (int j = 0; j < 8; j++) w[j] = __expf(leaky(q[j] + edi));
        #pragma unroll
        for (int j = 0; j < 8; j++) { den += w[j]; A.fma(u[j], w[j]); }
    }
    for (; e < e1; e++) {
        int s = csrsrc[e];
        float wt = __expf(leaky(es[s] + edi));
        uint4 u = h16[(size_t)s * 4 + l];
        den += wt;
        A.fma(u, wt);
    }
    {   // self-loop
        float wt = __expf(leaky(es[node] + edi));
        uint4 u = h16[(size_t)node * 4 + l];
        den += wt;
        A.fma(u, wt);
    }
    const float4* b4 = (const float4*)b;
    float4 bv0 = b4[2*l], bv1 = b4[2*l + 1];
    float inv = 1.f / den;
    float4 o0, o1;
    o0.x = A.a0*inv + bv0.x; o0.y = A.a1*inv + bv0.y; o0.z = A.a2*inv + bv0.z; o0.w = A.a3*inv + bv0.w;
    o1.x = A.a4*inv + bv1.x; o1.y = A.a5*inv + bv1.y; o1.z = A.a6*inv + bv1.z; o1.w = A.a7*inv + bv1.w;
    ((float4*)out)[(size_t)node*8 + 2*l]     = o0;
    ((float4*)out)[(size_t)node*8 + 2*l + 1] = o1;
}

// -------- Pool: one 64-lane wave per graph (batch sorted, binary search) ---

__global__ __launch_bounds__(256) void pool_graph(
    const float* __restrict__ x, const int* __restrict__ batch,
    float* __restrict__ out, int N, int G)
{
    const int g = (blockIdx.x * 256 + threadIdx.x) >> 6;   // wave id = graph id
    if (g >= G) return;
    const int lane = threadIdx.x & 63;
    const int feat = lane & 31;
    const int half = lane >> 5;

    int lo = 0, hi = N;
    while (lo < hi) { int mid = (lo + hi) >> 1; if (batch[mid] < g) lo = mid + 1; else hi = mid; }
    const int start = lo;
    int lo2 = start, hi2 = N;
    while (lo2 < hi2) { int mid = (lo2 + hi2) >> 1; if (batch[mid] < g + 1) lo2 = mid + 1; else hi2 = mid; }
    const int end = lo2;

    float acc = 0.f;
    for (int i = start + half; i < end; i += 2)
        acc += x[(size_t)i * HDIM + feat];
    acc += __shfl_xor(acc, 32);
    if (half == 0) {
        float cnt = (float)(end - start);
        out[(size_t)g * HDIM + feat] = acc / fmaxf(cnt, 1.f);
    }
}

// ---------------- Launch ----------------

extern "C" void kernel_launch(void* const* d_in, const int* in_sizes, int n_in,
                              void* d_out, int out_size, void* d_ws, size_t ws_size,
                              hipStream_t stream) {
    const float* x          = (const float*)d_in[0];
    const int*   edge_index = (const int*)d_in[1];
    const int*   batch      = (const int*)d_in[2];

    const int N = in_sizes[2];              // 100000
    const int E = in_sizes[1] / 2;          // 1600000
    const int G = out_size / HDIM;          // 2048
    const int B = (N + NPB - 1) / NPB;      // 782 buckets
    const int NBLK = (E + CHUNK - 1) / CHUNK;
    const int ntiles = (N + 63) / 64;

    const int* srcs = edge_index;
    const int* dsts = edge_index + E;

    // workspace layout (float4-accessed buffers first, 16B-aligned offsets)
    char* p = (char*)d_ws;
    __half* h     = (__half*)p; p += (size_t)N * HDIM * sizeof(__half);
    float* xbuf   = (float*)p; p += (size_t)N * HDIM * sizeof(float);
    float* es     = (float*)p; p += (size_t)N * sizeof(float);
    float* ed     = (float*)p; p += (size_t)N * sizeof(float);
    int*   rowptr = (int*)p;   p += (size_t)(N + 1) * sizeof(int);
    int*   csrsrc = (int*)p;   p += (size_t)E * sizeof(int);
    int*   pairs  = (int*)p;   p += (size_t)E * sizeof(int);
    int*   cnt2D  = (int*)p;   p += (size_t)NBLK * B * sizeof(int);
    int*   off2D  = (int*)p;   p += (size_t)NBLK * B * sizeof(int);
    int*   bcnt   = (int*)p;   p += (size_t)B * sizeof(int);
    int*   bstart = (int*)p;   p += (size_t)(B + 1) * sizeof(int);

    // ---- CSR build (once; same edge set for all 4 layers) ----
    chunk_hist  <<<NBLK, 256, 0, stream>>>(dsts, E, B, cnt2D);
    chunk_scan  <<<B, 256, 0, stream>>>(cnt2D, NBLK, B, off2D, bcnt);
    bucket_scan <<<1, 1024, 0, stream>>>(bcnt, B, E, bstart, rowptr, N);
    pair_scatter2<<<NBLK, 256, 0, stream>>>(srcs, dsts, E, B, off2D, bstart, pairs);
    bucket_sort <<<B, 256, 0, stream>>>(pairs, bstart, rowptr, csrsrc, N);

    // ---- 4 GAT layers ----
    for (int l = 0; l < 4; l++) {
        const float* W   = (const float*)d_in[3 + 4 * l];
        const float* a_s = (const float*)d_in[4 + 4 * l];
        const float* a_d = (const float*)d_in[5 + 4 * l];
        const float* bb  = (const float*)d_in[6 + 4 * l];

        if (l == 0) gemm_mfma<IN_DIM><<<ntiles, 256, 0, stream>>>(x, W, a_s, a_d, h, es, ed, N);
        else        gemm_mfma<HDIM>  <<<ntiles, 256, 0, stream>>>(xbuf, W, a_s, a_d, h, es, ed, N);

        agg4<<<(N * 4 + 255) / 256, 256, 0, stream>>>(h, es, ed, rowptr, csrsrc, bb, xbuf, N);
    }

    // ---- global mean pool: one wave per graph ----
    pool_graph<<<(G * 64 + 255) / 256, 256, 0, stream>>>(xbuf, batch, (float*)d_out, N, G);
}

// Round 10
// 346.511 us; speedup vs baseline: 1.3524x; 1.0207x over previous
//
#include <hip/hip_runtime.h>
#include <hip/hip_fp16.h>

#define HDIM 32
#define IN_DIM 128
#define NEG_SLOPE 0.2f
#define NPB 128            // nodes per coarse bucket (power of 2)
#define NPB_SHIFT 7
#define MAXB 1024          // max buckets (B = ceil(N/128) = 782)
#define CHUNK 8192         // edges per chunk block
#define CAP 4096           // max records per bucket for LDS sort fast path

typedef _Float16 half8  __attribute__((ext_vector_type(8)));
typedef _Float16 half4v __attribute__((ext_vector_type(4)));
typedef float    floatx4 __attribute__((ext_vector_type(4)));

__device__ __forceinline__ float leaky(float e) {
    return (e >= 0.f) ? e : NEG_SLOPE * e;
}

__device__ __forceinline__ float2 h2f(unsigned int u) {
    __half2 h = *reinterpret_cast<__half2*>(&u);
    return __half22float2(h);
}

// ------------- MFMA GEMM: h = x@W (fp16 in, fp32 acc), es/ed fused ---------

template<int K>
__global__ __launch_bounds__(256) void gemm_mfma(
    const float* __restrict__ x, const float* __restrict__ W,
    const float* __restrict__ a_s, const float* __restrict__ a_d,
    __half* __restrict__ h, float* __restrict__ es, float* __restrict__ ed, int N)
{
    constexpr int KP = K + 8;                 // +8 halves pad -> 2-way conflicts only
    __shared__ _Float16 xs[64 * KP];
    __shared__ _Float16 Wt[32 * KP];          // Wt[n][k] = W[k][n]
    const int tid = threadIdx.x;
    for (int i = tid; i < K * 32; i += 256) {
        int k = i >> 5, n = i & 31;
        Wt[n * KP + k] = (_Float16)W[i];
    }
    const int lane = tid & 63;
    const int wave = tid >> 6;                // 0..3
    const int m16  = lane & 15;
    const int quad = lane >> 4;               // 0..3
    const float as0 = a_s[m16], as1 = a_s[m16 + 16];
    const float ad0 = a_d[m16], ad1 = a_d[m16 + 16];

    const int ntiles = (N + 63) >> 6;
    for (int tile = blockIdx.x; tile < ntiles; tile += gridDim.x) {
        const int row0 = tile << 6;
        __syncthreads();
        for (int i = tid; i < 64 * (K / 4); i += 256) {
            int r  = i / (K / 4);
            int c4 = i % (K / 4);
            float4 v = (row0 + r < N) ? ((const float4*)x)[(size_t)(row0 + r) * (K / 4) + c4]
                                      : make_float4(0.f, 0.f, 0.f, 0.f);
            half4v hv = { (_Float16)v.x, (_Float16)v.y, (_Float16)v.z, (_Float16)v.w };
            *(half4v*)&xs[r * KP + c4 * 4] = hv;
        }
        __syncthreads();
        floatx4 acc0 = {0.f, 0.f, 0.f, 0.f}, acc1 = {0.f, 0.f, 0.f, 0.f};
        const int rbase = wave * 16;
        #pragma unroll
        for (int kt = 0; kt < K / 32; kt++) {
            half8 a  = *(half8*)&xs[(rbase + m16) * KP + kt * 32 + quad * 8];
            half8 b0 = *(half8*)&Wt[m16 * KP + kt * 32 + quad * 8];
            half8 b1 = *(half8*)&Wt[(m16 + 16) * KP + kt * 32 + quad * 8];
            acc0 = __builtin_amdgcn_mfma_f32_16x16x32_f16(a, b0, acc0, 0, 0, 0);
            acc1 = __builtin_amdgcn_mfma_f32_16x16x32_f16(a, b1, acc1, 0, 0, 0);
        }
        #pragma unroll
        for (int r = 0; r < 4; r++) {
            int row = row0 + rbase + quad * 4 + r;
            float c0 = acc0[r], c1 = acc1[r];
            float ps = c0 * as0 + c1 * as1;
            float pd = c0 * ad0 + c1 * ad1;
            #pragma unroll
            for (int m = 8; m >= 1; m >>= 1) { ps += __shfl_xor(ps, m); pd += __shfl_xor(pd, m); }
            if (row < N) {
                h[(size_t)row * HDIM + m16]      = __float2half(c0);
                h[(size_t)row * HDIM + m16 + 16] = __float2half(c1);
                if (m16 == 0) { es[row] = ps; ed[row] = pd; }
            }
        }
    }
}

// ---------------- Two-level CSR build (once per call) ----------------

__global__ __launch_bounds__(256) void chunk_hist(
    const int* __restrict__ dsts, int E, int B, int* __restrict__ cnt2D)
{
    __shared__ int hist[MAXB];
    const int blk = blockIdx.x;
    for (int i = threadIdx.x; i < B; i += 256) hist[i] = 0;
    __syncthreads();
    const int e0 = blk * CHUNK;
    for (int i = threadIdx.x; i < CHUNK; i += 256) {
        int e = e0 + i;
        if (e < E) atomicAdd(&hist[dsts[e] >> NPB_SHIFT], 1);
    }
    __syncthreads();
    for (int i = threadIdx.x; i < B; i += 256) cnt2D[(size_t)blk * B + i] = hist[i];
}

__global__ __launch_bounds__(256) void chunk_scan(
    const int* __restrict__ cnt2D, int NBLK, int B,
    int* __restrict__ off2D, int* __restrict__ bcnt)
{
    __shared__ int s[256];
    const int b = blockIdx.x, t = threadIdx.x;
    int v = (t < NBLK) ? cnt2D[(size_t)t * B + b] : 0;
    s[t] = v;
    __syncthreads();
    for (int off = 1; off < 256; off <<= 1) {
        int add = (t >= off) ? s[t - off] : 0;
        __syncthreads();
        s[t] += add;
        __syncthreads();
    }
    if (t < NBLK) off2D[(size_t)t * B + b] = s[t] - v;
    if (t == 255) bcnt[b] = s[255];
}

__global__ __launch_bounds__(1024) void bucket_scan(
    const int* __restrict__ bcnt, int B, int E,
    int* __restrict__ bstart, int* __restrict__ rowptr, int N)
{
    __shared__ int s[1024];
    const int t = threadIdx.x;
    int v = (t < B) ? bcnt[t] : 0;
    s[t] = v;
    __syncthreads();
    for (int off = 1; off < 1024; off <<= 1) {
        int add = (t >= off) ? s[t - off] : 0;
        __syncthreads();
        s[t] += add;
        __syncthreads();
    }
    if (t < B) bstart[t] = s[t] - v;
    if (t == 0) { bstart[B] = E; rowptr[N] = E; }
}

__global__ __launch_bounds__(256) void pair_scatter2(
    const int* __restrict__ srcs, const int* __restrict__ dsts, int E, int B,
    const int* __restrict__ off2D, const int* __restrict__ bstart,
    int* __restrict__ pairs)
{
    __shared__ int cur[MAXB];
    const int blk = blockIdx.x;
    for (int i = threadIdx.x; i < B; i += 256)
        cur[i] = bstart[i] + off2D[(size_t)blk * B + i];
    __syncthreads();
    const int e0 = blk * CHUNK;
    for (int i = threadIdx.x; i < CHUNK; i += 256) {
        int e = e0 + i;
        if (e < E) {
            int s = srcs[e], d = dsts[e];
            int pos = atomicAdd(&cur[d >> NPB_SHIFT], 1);
            pairs[pos] = (s << NPB_SHIFT) | (d & (NPB - 1));
        }
    }
}

__global__ __launch_bounds__(256) void bucket_sort(
    const int* __restrict__ pairs, const int* __restrict__ bstart,
    int* __restrict__ rowptr, int* __restrict__ csrsrc, int N)
{
    __shared__ int ldeg[NPB];
    __shared__ int lex[NPB];
    __shared__ int recs[CAP];
    __shared__ int sorted[CAP];
    const int b = blockIdx.x, t = threadIdx.x;
    const int p0 = bstart[b], p1 = bstart[b + 1];
    const int cnt = p1 - p0;
    if (t < NPB) ldeg[t] = 0;
    __syncthreads();
    for (int i = t; i < cnt; i += 256) {
        int r = pairs[p0 + i];
        atomicAdd(&ldeg[r & (NPB - 1)], 1);
        if (i < CAP) recs[i] = r;
    }
    __syncthreads();
    if (t < NPB) lex[t] = ldeg[t];
    __syncthreads();
    for (int off = 1; off < NPB; off <<= 1) {
        int add = (t >= off && t < NPB) ? lex[t - off] : 0;
        __syncthreads();
        if (t < NPB) lex[t] += add;
        __syncthreads();
    }
    const int node0 = b * NPB;
    if (t < NPB) {
        int excl = lex[t] - ldeg[t];
        if (node0 + t < N) rowptr[node0 + t] = p0 + excl;
        ldeg[t] = excl;
    }
    __syncthreads();
    if (cnt <= CAP) {
        for (int i = t; i < cnt; i += 256) {
            int r = recs[i];
            int pos = atomicAdd(&ldeg[r & (NPB - 1)], 1);
            sorted[pos] = r >> NPB_SHIFT;
        }
        __syncthreads();
        for (int i = t; i < cnt; i += 256) csrsrc[p0 + i] = sorted[i];
    } else {
        for (int i = t; i < cnt; i += 256) {
            int r = pairs[p0 + i];
            int pos = atomicAdd(&ldeg[r & (NPB - 1)], 1);
            csrsrc[p0 + pos] = r >> NPB_SHIFT;
        }
    }
}

// -------- Aggregation: 4 lanes/node, es recomputed in-register ------------
// es[s] = a_s . h_row_s ; the 4-lane group holds the whole row, so the random
// es gather (1 transaction/edge) is replaced by 8 FMAs + 2 intra-group shuffles.

__global__ __launch_bounds__(256) void agg5(
    const __half* __restrict__ h, const float* __restrict__ es, const float* __restrict__ ed,
    const int* __restrict__ rowptr, const int* __restrict__ csrsrc,
    const float* __restrict__ a_s, const float* __restrict__ b,
    float* __restrict__ out, int N)
{
    const int gid  = blockIdx.x * 256 + threadIdx.x;
    const int node = gid >> 2;
    const int l    = threadIdx.x & 3;
    if (node >= N) return;

    const int e0 = rowptr[node];
    const int e1 = rowptr[node + 1];
    const float edi = ed[node];
    const uint4* __restrict__ h16 = (const uint4*)h;   // row = 4 uint4 of 8 halves

    float asf[8];
    #pragma unroll
    for (int i = 0; i < 8; i++) asf[i] = a_s[l * 8 + i];

    float a0=0.f,a1=0.f,a2=0.f,a3=0.f,a4=0.f,a5=0.f,a6=0.f,a7=0.f,den=0.f;

    int e = e0;
    for (; e + 8 <= e1; e += 8) {
        int s[8]; uint4 u[8];
        #pragma unroll
        for (int j = 0; j < 8; j++) s[j] = csrsrc[e + j];
        #pragma unroll
        for (int j = 0; j < 8; j++) u[j] = h16[(size_t)s[j] * 4 + l];
        #pragma unroll
        for (int j = 0; j < 8; j++) {
            float2 f0 = h2f(u[j].x), f1 = h2f(u[j].y), f2 = h2f(u[j].z), f3 = h2f(u[j].w);
            float dot = asf[0]*f0.x + asf[1]*f0.y + asf[2]*f1.x + asf[3]*f1.y
                      + asf[4]*f2.x + asf[5]*f2.y + asf[6]*f3.x + asf[7]*f3.y;
            dot += __shfl_xor(dot, 1);
            dot += __shfl_xor(dot, 2);
            float w = __expf(leaky(dot + edi));
            den += w;
            a0 += w*f0.x; a1 += w*f0.y; a2 += w*f1.x; a3 += w*f1.y;
            a4 += w*f2.x; a5 += w*f2.y; a6 += w*f3.x; a7 += w*f3.y;
        }
    }
    for (; e < e1; e++) {
        int s = csrsrc[e];
        uint4 u = h16[(size_t)s * 4 + l];
        float2 f0 = h2f(u.x), f1 = h2f(u.y), f2 = h2f(u.z), f3 = h2f(u.w);
        float dot = asf[0]*f0.x + asf[1]*f0.y + asf[2]*f1.x + asf[3]*f1.y
                  + asf[4]*f2.x + asf[5]*f2.y + asf[6]*f3.x + asf[7]*f3.y;
        dot += __shfl_xor(dot, 1);
        dot += __shfl_xor(dot, 2);
        float w = __expf(leaky(dot + edi));
        den += w;
        a0 += w*f0.x; a1 += w*f0.y; a2 += w*f1.x; a3 += w*f1.y;
        a4 += w*f2.x; a5 += w*f2.y; a6 += w*f3.x; a7 += w*f3.y;
    }
    {   // self-loop: exact es from the gemm epilogue
        float wt = __expf(leaky(es[node] + edi));
        uint4 u = h16[(size_t)node * 4 + l];
        float2 f0 = h2f(u.x), f1 = h2f(u.y), f2 = h2f(u.z), f3 = h2f(u.w);
        den += wt;
        a0 += wt*f0.x; a1 += wt*f0.y; a2 += wt*f1.x; a3 += wt*f1.y;
        a4 += wt*f2.x; a5 += wt*f2.y; a6 += wt*f3.x; a7 += wt*f3.y;
    }
    const float4* b4 = (const float4*)b;
    float4 bv0 = b4[2*l], bv1 = b4[2*l + 1];
    float inv = 1.f / den;
    float4 o0, o1;
    o0.x = a0*inv + bv0.x; o0.y = a1*inv + bv0.y; o0.z = a2*inv + bv0.z; o0.w = a3*inv + bv0.w;
    o1.x = a4*inv + bv1.x; o1.y = a5*inv + bv1.y; o1.z = a6*inv + bv1.z; o1.w = a7*inv + bv1.w;
    ((float4*)out)[(size_t)node*8 + 2*l]     = o0;
    ((float4*)out)[(size_t)node*8 + 2*l + 1] = o1;
}

// -------- Pool: one 64-lane wave per graph (batch sorted, binary search) ---

__global__ __launch_bounds__(256) void pool_graph(
    const float* __restrict__ x, const int* __restrict__ batch,
    float* __restrict__ out, int N, int G)
{
    const int g = (blockIdx.x * 256 + threadIdx.x) >> 6;   // wave id = graph id
    if (g >= G) return;
    const int lane = threadIdx.x & 63;
    const int feat = lane & 31;
    const int half = lane >> 5;

    int lo = 0, hi = N;
    while (lo < hi) { int mid = (lo + hi) >> 1; if (batch[mid] < g) lo = mid + 1; else hi = mid; }
    const int start = lo;
    int lo2 = start, hi2 = N;
    while (lo2 < hi2) { int mid = (lo2 + hi2) >> 1; if (batch[mid] < g + 1) lo2 = mid + 1; else hi2 = mid; }
    const int end = lo2;

    float acc = 0.f;
    for (int i = start + half; i < end; i += 2)
        acc += x[(size_t)i * HDIM + feat];
    acc += __shfl_xor(acc, 32);
    if (half == 0) {
        float cnt = (float)(end - start);
        out[(size_t)g * HDIM + feat] = acc / fmaxf(cnt, 1.f);
    }
}

// ---------------- Launch ----------------

extern "C" void kernel_launch(void* const* d_in, const int* in_sizes, int n_in,
                              void* d_out, int out_size, void* d_ws, size_t ws_size,
                              hipStream_t stream) {
    const float* x          = (const float*)d_in[0];
    const int*   edge_index = (const int*)d_in[1];
    const int*   batch      = (const int*)d_in[2];

    const int N = in_sizes[2];              // 100000
    const int E = in_sizes[1] / 2;          // 1600000
    const int G = out_size / HDIM;          // 2048
    const int B = (N + NPB - 1) / NPB;      // 782 buckets
    const int NBLK = (E + CHUNK - 1) / CHUNK;
    const int ntiles = (N + 63) / 64;

    const int* srcs = edge_index;
    const int* dsts = edge_index + E;

    // workspace layout (float4-accessed buffers first, 16B-aligned offsets)
    char* p = (char*)d_ws;
    __half* h     = (__half*)p; p += (size_t)N * HDIM * sizeof(__half);
    float* xbuf   = (float*)p; p += (size_t)N * HDIM * sizeof(float);
    float* es     = (float*)p; p += (size_t)N * sizeof(float);
    float* ed     = (float*)p; p += (size_t)N * sizeof(float);
    int*   rowptr = (int*)p;   p += (size_t)(N + 1) * sizeof(int);
    int*   csrsrc = (int*)p;   p += (size_t)E * sizeof(int);
    int*   pairs  = (int*)p;   p += (size_t)E * sizeof(int);
    int*   cnt2D  = (int*)p;   p += (size_t)NBLK * B * sizeof(int);
    int*   off2D  = (int*)p;   p += (size_t)NBLK * B * sizeof(int);
    int*   bcnt   = (int*)p;   p += (size_t)B * sizeof(int);
    int*   bstart = (int*)p;   p += (size_t)(B + 1) * sizeof(int);

    // ---- CSR build (once; same edge set for all 4 layers) ----
    chunk_hist  <<<NBLK, 256, 0, stream>>>(dsts, E, B, cnt2D);
    chunk_scan  <<<B, 256, 0, stream>>>(cnt2D, NBLK, B, off2D, bcnt);
    bucket_scan <<<1, 1024, 0, stream>>>(bcnt, B, E, bstart, rowptr, N);
    pair_scatter2<<<NBLK, 256, 0, stream>>>(srcs, dsts, E, B, off2D, bstart, pairs);
    bucket_sort <<<B, 256, 0, stream>>>(pairs, bstart, rowptr, csrsrc, N);

    // ---- 4 GAT layers ----
    for (int l = 0; l < 4; l++) {
        const float* W   = (const float*)d_in[3 + 4 * l];
        const float* a_s = (const float*)d_in[4 + 4 * l];
        const float* a_d = (const float*)d_in[5 + 4 * l];
        const float* bb  = (const float*)d_in[6 + 4 * l];

        if (l == 0) gemm_mfma<IN_DIM><<<ntiles, 256, 0, stream>>>(x, W, a_s, a_d, h, es, ed, N);
        else        gemm_mfma<HDIM>  <<<ntiles, 256, 0, stream>>>(xbuf, W, a_s, a_d, h, es, ed, N);

        agg5<<<(N * 4 + 255) / 256, 256, 0, stream>>>(h, es, ed, rowptr, csrsrc, a_s, bb, xbuf, N);
    }

    // ---- global mean pool: one wave per graph ----
    pool_graph<<<(G * 64 + 255) / 256, 256, 0, stream>>>(xbuf, batch, (float*)d_out, N, G);
}